// Round 6
// baseline (2211.249 us; speedup 1.0000x reference)
//
#include <hip/hip_runtime.h>
#include <hip/hip_bf16.h>

#define LRELU(v, s) ((v) > 0.0f ? (v) : (s) * (v))

// --- bf16x2 pack/unpack (RNE) ---------------------------------------------
__device__ __forceinline__ unsigned pack_bf16x2(float lo, float hi) {
    unsigned a = __builtin_bit_cast(unsigned, lo);
    unsigned b = __builtin_bit_cast(unsigned, hi);
    a += 0x7fffu + ((a >> 16) & 1u);
    b += 0x7fffu + ((b >> 16) & 1u);
    return (a >> 16) | (b & 0xffff0000u);
}
__device__ __forceinline__ float bf_lo(unsigned u) {
    return __builtin_bit_cast(float, u << 16);
}
__device__ __forceinline__ float bf_hi(unsigned u) {
    return __builtin_bit_cast(float, u & 0xffff0000u);
}

// ---------------------------------------------------------------------------
// GEMM1 + fused scores.  h1p[N,64(u32)] = bf16x2(x @ W1), es/ed[N,4] fp32.
// 64-row tiles, k in 4 chunks of 32, DOUBLE-BUFFERED (2 x 24KB = 48KB LDS,
// 3 blocks/CU): chunk c+1's global loads issue into registers BEFORE chunk
// c's FMAs (async-stage split), ds_write after -> HBM latency hidden, one
// barrier per chunk.  Thread = 8 rows x 4 cols, all-float4 LDS reads.
// ---------------------------------------------------------------------------
__global__ __launch_bounds__(256, 3) void gemm1_kernel(const float* __restrict__ x,
                                                       const float* __restrict__ W,
                                                       const float* __restrict__ asrc,
                                                       const float* __restrict__ adst,
                                                       unsigned* __restrict__ h1p,
                                                       float* __restrict__ es,
                                                       float* __restrict__ ed,
                                                       int N, int ntiles) {
    __shared__ float sX[2][64 * 32];    // 8 KB each (64 rows x 32 k)
    __shared__ float sW[2][32 * 128];   // 16 KB each (32 k x 128 cols)
    const int tid = threadIdx.x;
    const int jq = tid & 31;    // col quad -> cols 4jq..4jq+3 (head = jq>>3)
    const int trow = tid >> 5;  // row group -> rows trow*8..trow*8+7
    const float4 asv = *(const float4*)&asrc[jq * 4];
    const float4 adv = *(const float4*)&adst[jq * 4];
    // staging slots for this thread (2 sX float4s, 4 sW float4s per chunk)
    const int xs0 = tid, xs1 = tid + 256;              // sX slot ids (of 512)
    const int xr0 = xs0 >> 3, xk0 = xs0 & 7;
    const int xr1 = xs1 >> 3, xk1 = xs1 & 7;

    for (int tile = blockIdx.x; tile < ntiles; tile += gridDim.x) {
        const int row0 = tile * 64;
        // ---- stage chunk 0 directly ----
        {
            float4 v0 = {0,0,0,0}, v1 = {0,0,0,0};
            if (row0 + xr0 < N) v0 = *(const float4*)&x[(size_t)(row0 + xr0) * 128 + xk0 * 4];
            if (row0 + xr1 < N) v1 = *(const float4*)&x[(size_t)(row0 + xr1) * 128 + xk1 * 4];
            *(float4*)&sX[0][xr0 * 32 + xk0 * 4] = v0;
            *(float4*)&sX[0][xr1 * 32 + xk1 * 4] = v1;
#pragma unroll
            for (int j = 0; j < 4; ++j) {
                const int s = tid + j * 256, kr = s >> 5, cq = s & 31;
                *(float4*)&sW[0][kr * 128 + cq * 4] = *(const float4*)&W[(size_t)kr * 128 + cq * 4];
            }
        }
        __syncthreads();
        float acc[8][4] = {};
#pragma unroll
        for (int c = 0; c < 4; ++c) {
            const int cur = c & 1, nxt = cur ^ 1;
            // ---- issue next chunk's global loads (registers) ----
            float4 px0, px1, pw0, pw1, pw2, pw3;
            if (c < 3) {
                const int k0 = (c + 1) * 32;
                px0 = px1 = make_float4(0.f, 0.f, 0.f, 0.f);
                if (row0 + xr0 < N) px0 = *(const float4*)&x[(size_t)(row0 + xr0) * 128 + k0 + xk0 * 4];
                if (row0 + xr1 < N) px1 = *(const float4*)&x[(size_t)(row0 + xr1) * 128 + k0 + xk1 * 4];
                const int s0 = tid, s1 = tid + 256, s2 = tid + 512, s3 = tid + 768;
                pw0 = *(const float4*)&W[(size_t)(k0 + (s0 >> 5)) * 128 + (s0 & 31) * 4];
                pw1 = *(const float4*)&W[(size_t)(k0 + (s1 >> 5)) * 128 + (s1 & 31) * 4];
                pw2 = *(const float4*)&W[(size_t)(k0 + (s2 >> 5)) * 128 + (s2 & 31) * 4];
                pw3 = *(const float4*)&W[(size_t)(k0 + (s3 >> 5)) * 128 + (s3 & 31) * 4];
            }
            // ---- compute current chunk ----
#pragma unroll
            for (int kk = 0; kk < 32; kk += 4) {
                const float4 w0 = *(float4*)&sW[cur][(kk + 0) * 128 + jq * 4];
                const float4 w1 = *(float4*)&sW[cur][(kk + 1) * 128 + jq * 4];
                const float4 w2 = *(float4*)&sW[cur][(kk + 2) * 128 + jq * 4];
                const float4 w3 = *(float4*)&sW[cur][(kk + 3) * 128 + jq * 4];
#pragma unroll
                for (int r = 0; r < 8; ++r) {
                    const float4 xv = *(float4*)&sX[cur][(trow * 8 + r) * 32 + kk];
                    acc[r][0] = fmaf(xv.x, w0.x, fmaf(xv.y, w1.x, fmaf(xv.z, w2.x, fmaf(xv.w, w3.x, acc[r][0]))));
                    acc[r][1] = fmaf(xv.x, w0.y, fmaf(xv.y, w1.y, fmaf(xv.z, w2.y, fmaf(xv.w, w3.y, acc[r][1]))));
                    acc[r][2] = fmaf(xv.x, w0.z, fmaf(xv.y, w1.z, fmaf(xv.z, w2.z, fmaf(xv.w, w3.z, acc[r][2]))));
                    acc[r][3] = fmaf(xv.x, w0.w, fmaf(xv.y, w1.w, fmaf(xv.z, w2.w, fmaf(xv.w, w3.w, acc[r][3]))));
                }
            }
            // ---- write next chunk to LDS ----
            if (c < 3) {
                *(float4*)&sX[nxt][xr0 * 32 + xk0 * 4] = px0;
                *(float4*)&sX[nxt][xr1 * 32 + xk1 * 4] = px1;
                const int s0 = tid, s1 = tid + 256, s2 = tid + 512, s3 = tid + 768;
                *(float4*)&sW[nxt][(s0 >> 5) * 128 + (s0 & 31) * 4] = pw0;
                *(float4*)&sW[nxt][(s1 >> 5) * 128 + (s1 & 31) * 4] = pw1;
                *(float4*)&sW[nxt][(s2 >> 5) * 128 + (s2 & 31) * 4] = pw2;
                *(float4*)&sW[nxt][(s3 >> 5) * 128 + (s3 & 31) * 4] = pw3;
            }
            __syncthreads();
        }
        // ---- epilogue: scores + bf16x2 pack ----
#pragma unroll
        for (int r = 0; r < 8; ++r) {
            const int row = row0 + trow * 8 + r;
            float ps = acc[r][0] * asv.x + acc[r][1] * asv.y + acc[r][2] * asv.z + acc[r][3] * asv.w;
            float pd = acc[r][0] * adv.x + acc[r][1] * adv.y + acc[r][2] * adv.z + acc[r][3] * adv.w;
#pragma unroll
            for (int off = 1; off <= 4; off <<= 1) {
                ps += __shfl_xor(ps, off);
                pd += __shfl_xor(pd, off);
            }
            if (row < N) {
                if ((jq & 7) == 0) {
                    es[row * 4 + (jq >> 3)] = ps;
                    ed[row * 4 + (jq >> 3)] = pd;
                }
                *(uint2*)&h1p[(size_t)row * 64 + jq * 2] =
                    make_uint2(pack_bf16x2(acc[r][0], acc[r][1]),
                               pack_bf16x2(acc[r][2], acc[r][3]));
            }
        }
    }
}

// ---------------------------------------------------------------------------
// GEMM2 + fused scores: h2p[N,32(u32)] = bf16x2(x2 @ W2), es2/ed2[N] fp32.
// Same double-buffered async-stage structure; k in 2 chunks of 64; x2p staged
// PACKED (u32), unpacked in-register.  48KB LDS, 3 blocks/CU.
// ---------------------------------------------------------------------------
__global__ __launch_bounds__(256, 3) void gemm2_kernel(const unsigned* __restrict__ x2p,
                                                       const float* __restrict__ W,
                                                       const float* __restrict__ asrc,
                                                       const float* __restrict__ adst,
                                                       unsigned* __restrict__ h2p,
                                                       float* __restrict__ es,
                                                       float* __restrict__ ed,
                                                       int N, int ntiles) {
    __shared__ float sW[2][64 * 64];       // 16 KB each (64 k x 64 cols)
    __shared__ unsigned sX[2][64 * 32];    // 8 KB each (64 rows x 32 u32)
    const int tid = threadIdx.x;
    const int cg = tid & 15;    // cols 4cg..4cg+3
    const int trow = tid >> 4;  // rows trow*4..trow*4+3
    const float4 asv = *(const float4*)&asrc[cg * 4];
    const float4 adv = *(const float4*)&adst[cg * 4];
    const int xs0 = tid, xs1 = tid + 256;
    const int xr0 = xs0 >> 3, xk0 = xs0 & 7;
    const int xr1 = xs1 >> 3, xk1 = xs1 & 7;

    for (int tile = blockIdx.x; tile < ntiles; tile += gridDim.x) {
        const int row0 = tile * 64;
        {
            uint4 v0 = {0,0,0,0}, v1 = {0,0,0,0};
            if (row0 + xr0 < N) v0 = *(const uint4*)&x2p[(size_t)(row0 + xr0) * 64 + xk0 * 4];
            if (row0 + xr1 < N) v1 = *(const uint4*)&x2p[(size_t)(row0 + xr1) * 64 + xk1 * 4];
            *(uint4*)&sX[0][xr0 * 32 + xk0 * 4] = v0;
            *(uint4*)&sX[0][xr1 * 32 + xk1 * 4] = v1;
#pragma unroll
            for (int j = 0; j < 4; ++j) {
                const int s = tid + j * 256, kr = s >> 4, cq = s & 15;
                *(float4*)&sW[0][kr * 64 + cq * 4] = *(const float4*)&W[(size_t)kr * 64 + cq * 4];
            }
        }
        __syncthreads();
        float acc[4][4] = {};
#pragma unroll
        for (int c = 0; c < 2; ++c) {
            const int cur = c & 1, nxt = cur ^ 1;
            uint4 px0, px1;
            float4 pw0, pw1, pw2, pw3;
            if (c < 1) {
                const int k0 = 64, c0 = 32;
                px0 = make_uint4(0,0,0,0); px1 = make_uint4(0,0,0,0);
                if (row0 + xr0 < N) px0 = *(const uint4*)&x2p[(size_t)(row0 + xr0) * 64 + c0 + xk0 * 4];
                if (row0 + xr1 < N) px1 = *(const uint4*)&x2p[(size_t)(row0 + xr1) * 64 + c0 + xk1 * 4];
                const int s0 = tid, s1 = tid + 256, s2 = tid + 512, s3 = tid + 768;
                pw0 = *(const float4*)&W[(size_t)(k0 + (s0 >> 4)) * 64 + (s0 & 15) * 4];
                pw1 = *(const float4*)&W[(size_t)(k0 + (s1 >> 4)) * 64 + (s1 & 15) * 4];
                pw2 = *(const float4*)&W[(size_t)(k0 + (s2 >> 4)) * 64 + (s2 & 15) * 4];
                pw3 = *(const float4*)&W[(size_t)(k0 + (s3 >> 4)) * 64 + (s3 & 15) * 4];
            }
#pragma unroll
            for (int kk = 0; kk < 64; kk += 4) {
                const float4 w0 = *(float4*)&sW[cur][(kk + 0) * 64 + cg * 4];
                const float4 w1 = *(float4*)&sW[cur][(kk + 1) * 64 + cg * 4];
                const float4 w2 = *(float4*)&sW[cur][(kk + 2) * 64 + cg * 4];
                const float4 w3 = *(float4*)&sW[cur][(kk + 3) * 64 + cg * 4];
#pragma unroll
                for (int r = 0; r < 4; ++r) {
                    const uint2 u = *(uint2*)&sX[cur][(trow * 4 + r) * 32 + (kk >> 1)];
                    const float xv0 = bf_lo(u.x), xv1 = bf_hi(u.x);
                    const float xv2 = bf_lo(u.y), xv3 = bf_hi(u.y);
                    acc[r][0] = fmaf(xv0, w0.x, fmaf(xv1, w1.x, fmaf(xv2, w2.x, fmaf(xv3, w3.x, acc[r][0]))));
                    acc[r][1] = fmaf(xv0, w0.y, fmaf(xv1, w1.y, fmaf(xv2, w2.y, fmaf(xv3, w3.y, acc[r][1]))));
                    acc[r][2] = fmaf(xv0, w0.z, fmaf(xv1, w1.z, fmaf(xv2, w2.z, fmaf(xv3, w3.z, acc[r][2]))));
                    acc[r][3] = fmaf(xv0, w0.w, fmaf(xv1, w1.w, fmaf(xv2, w2.w, fmaf(xv3, w3.w, acc[r][3]))));
                }
            }
            if (c < 1) {
                *(uint4*)&sX[nxt][xr0 * 32 + xk0 * 4] = px0;
                *(uint4*)&sX[nxt][xr1 * 32 + xk1 * 4] = px1;
                const int s0 = tid, s1 = tid + 256, s2 = tid + 512, s3 = tid + 768;
                *(float4*)&sW[nxt][(s0 >> 4) * 64 + (s0 & 15) * 4] = pw0;
                *(float4*)&sW[nxt][(s1 >> 4) * 64 + (s1 & 15) * 4] = pw1;
                *(float4*)&sW[nxt][(s2 >> 4) * 64 + (s2 & 15) * 4] = pw2;
                *(float4*)&sW[nxt][(s3 >> 4) * 64 + (s3 & 15) * 4] = pw3;
            }
            __syncthreads();
        }
#pragma unroll
        for (int r = 0; r < 4; ++r) {
            const int row = row0 + trow * 4 + r;
            float ps = acc[r][0] * asv.x + acc[r][1] * asv.y + acc[r][2] * asv.z + acc[r][3] * asv.w;
            float pd = acc[r][0] * adv.x + acc[r][1] * adv.y + acc[r][2] * adv.z + acc[r][3] * adv.w;
#pragma unroll
            for (int off = 1; off <= 8; off <<= 1) {
                ps += __shfl_xor(ps, off);
                pd += __shfl_xor(pd, off);
            }
            if (row < N) {
                if (cg == 0) { es[row] = ps; ed[row] = pd; }
                *(uint2*)&h2p[(size_t)row * 32 + cg * 2] =
                    make_uint2(pack_bf16x2(acc[r][0], acc[r][1]),
                               pack_bf16x2(acc[r][2], acc[r][3]));
            }
        }
    }
}

// ---------------------------------------------------------------------------
// rank_count: one returning atomic per edge, MLP-pipelined — 4 independent
// atomics in flight per thread (manual unroll over grid-stride offsets).
// ---------------------------------------------------------------------------
__global__ __launch_bounds__(256) void rank_count_kernel(const int* __restrict__ ei, int E,
                                                         int* __restrict__ deg,
                                                         int* __restrict__ rank) {
    const int stride = gridDim.x * 256;
    int e = blockIdx.x * 256 + threadIdx.x;
    for (; e + 3 * stride < E; e += 4 * stride) {
        const int d0 = ei[E + e];
        const int d1 = ei[E + e + stride];
        const int d2 = ei[E + e + 2 * stride];
        const int d3 = ei[E + e + 3 * stride];
        const int r0 = atomicAdd(&deg[d0], 1);
        const int r1 = atomicAdd(&deg[d1], 1);
        const int r2 = atomicAdd(&deg[d2], 1);
        const int r3 = atomicAdd(&deg[d3], 1);
        rank[e] = r0;
        rank[e + stride] = r1;
        rank[e + 2 * stride] = r2;
        rank[e + 3 * stride] = r3;
    }
    for (; e < E; e += stride)
        rank[e] = atomicAdd(&deg[ei[E + e]], 1);
}

// ---------------------------------------------------------------------------
// CSR build: scan of (deg+1), then atomic-free fill; self-loop takes the
// deterministic LAST slot per segment.
// ---------------------------------------------------------------------------
__global__ __launch_bounds__(256) void scan_p1_kernel(const int* __restrict__ deg,
                                                      int* __restrict__ excl,
                                                      int* __restrict__ bsum, int N) {
    __shared__ int lds[256];
    const int tid = threadIdx.x;
    const int base = blockIdx.x * 2048;
    const int idx0 = base + tid * 8;
    int v[8];
    int s = 0;
#pragma unroll
    for (int i = 0; i < 8; ++i) {
        v[i] = (idx0 + i < N) ? deg[idx0 + i] + 1 : 0;  // +1 = self-loop
        s += v[i];
    }
    lds[tid] = s;
    __syncthreads();
    for (int off = 1; off < 256; off <<= 1) {
        int t = (tid >= off) ? lds[tid - off] : 0;
        __syncthreads();
        lds[tid] += t;
        __syncthreads();
    }
    const int texcl = lds[tid] - s;
    if (tid == 255) bsum[blockIdx.x] = lds[255];
    int run = texcl;
#pragma unroll
    for (int i = 0; i < 8; ++i) {
        if (idx0 + i < N) excl[idx0 + i] = run;
        run += v[i];
    }
}

__global__ void scan_p2_kernel(int* __restrict__ bsum, int nchunks) {
    const int lane = threadIdx.x;
    int v = (lane < nchunks) ? bsum[lane] : 0;
    const int orig = v;
#pragma unroll
    for (int off = 1; off < 64; off <<= 1) {
        int t = __shfl_up(v, off);
        if (lane >= off) v += t;
    }
    if (lane < nchunks) bsum[lane] = v - orig;
}

__global__ void scan_p3_kernel(const int* __restrict__ excl, const int* __restrict__ bsum,
                               int* __restrict__ rowstart, int N, int Etot) {
    const int i = blockIdx.x * 256 + threadIdx.x;
    if (i < N) rowstart[i] = excl[i] + bsum[i >> 11];
    if (i == 0) rowstart[N] = Etot;
}

__global__ void csr_fill_kernel(const int* __restrict__ ei, int E, int N,
                                const int* __restrict__ rowstart,
                                const int* __restrict__ rank,
                                int* __restrict__ csr_src) {
    const int e = blockIdx.x * 256 + threadIdx.x;
    if (e < E) {
        const int d = ei[E + e];
        csr_src[rowstart[d] + rank[e]] = ei[e];
    } else if (e < E + N) {
        const int d = e - E;
        csr_src[rowstart[d + 1] - 1] = d;
    }
}

// ---------------------------------------------------------------------------
// Aggregation layer 1: wave per dst node; lane covers channels {2l, 2l+1}
// (both in head l>>4 -> ONE exp per lane per edge). Single pass (logits
// bounded, fp32 exp exact for softmax ratio), 4-edge unroll. bf16x2 gather.
// ---------------------------------------------------------------------------
__global__ __launch_bounds__(256) void aggregate1_kernel(const unsigned* __restrict__ h1p,
                                                         const float* __restrict__ es,
                                                         const float* __restrict__ ed,
                                                         const int* __restrict__ rowstart,
                                                         const int* __restrict__ csr_src,
                                                         const float* __restrict__ b,
                                                         unsigned* __restrict__ x2p, int N) {
    const int n = (blockIdx.x * 256 + threadIdx.x) >> 6;
    const int lane = threadIdx.x & 63;
    if (n >= N) return;
    const int hh = lane >> 4;  // head 0..3
    const float edv = ed[n * 4 + hh];
    const int beg = rowstart[n], end = rowstart[n + 1];

    float acc0 = 0.f, acc1 = 0.f, den = 0.f;
    int j = beg;
    const int end4 = beg + ((end - beg) & ~3);
    for (; j < end4; j += 4) {
        const int s0 = csr_src[j], s1 = csr_src[j + 1];
        const int s2 = csr_src[j + 2], s3 = csr_src[j + 3];
        const unsigned u0 = h1p[(size_t)s0 * 64 + lane];
        const unsigned u1 = h1p[(size_t)s1 * 64 + lane];
        const unsigned u2 = h1p[(size_t)s2 * 64 + lane];
        const unsigned u3 = h1p[(size_t)s3 * 64 + lane];
        const float e0 = es[s0 * 4 + hh], e1 = es[s1 * 4 + hh];
        const float e2 = es[s2 * 4 + hh], e3 = es[s3 * 4 + hh];
        const float p0 = __expf(LRELU(e0 + edv, 0.2f));
        const float p1 = __expf(LRELU(e1 + edv, 0.2f));
        const float p2 = __expf(LRELU(e2 + edv, 0.2f));
        const float p3 = __expf(LRELU(e3 + edv, 0.2f));
        den += (p0 + p1) + (p2 + p3);
        acc0 = fmaf(p0, bf_lo(u0), fmaf(p1, bf_lo(u1), fmaf(p2, bf_lo(u2), fmaf(p3, bf_lo(u3), acc0))));
        acc1 = fmaf(p0, bf_hi(u0), fmaf(p1, bf_hi(u1), fmaf(p2, bf_hi(u2), fmaf(p3, bf_hi(u3), acc1))));
    }
    for (; j < end; ++j) {
        const int s = csr_src[j];
        const unsigned u = h1p[(size_t)s * 64 + lane];
        const float p = __expf(LRELU(es[s * 4 + hh] + edv, 0.2f));
        den += p;
        acc0 = fmaf(p, bf_lo(u), acc0);
        acc1 = fmaf(p, bf_hi(u), acc1);
    }
    const float2 bb = *(const float2*)&b[lane * 2];
    float o0 = acc0 / den + bb.x;  o0 = LRELU(o0, 0.01f);
    float o1 = acc1 / den + bb.y;  o1 = LRELU(o1, 0.01f);
    x2p[(size_t)n * 64 + lane] = pack_bf16x2(o0, o1);
}

// ---------------------------------------------------------------------------
// Aggregation layer 2: wave per dst node, TWO edges in flight per iteration
// (half-wave each; lane covers channels {2c, 2c+1}); unroll-4 -> 8 edges.
// ---------------------------------------------------------------------------
__global__ __launch_bounds__(256) void aggregate2_kernel(const unsigned* __restrict__ h2p,
                                                         const float* __restrict__ es,
                                                         const float* __restrict__ ed,
                                                         const int* __restrict__ rowstart,
                                                         const int* __restrict__ csr_src,
                                                         const float* __restrict__ b,
                                                         float* __restrict__ out, int N) {
    const int n = (blockIdx.x * 256 + threadIdx.x) >> 6;
    const int lane = threadIdx.x & 63;
    if (n >= N) return;
    const int half = lane >> 5, c = lane & 31;
    const float edv = ed[n];
    const int beg = rowstart[n], end = rowstart[n + 1];

    float acc0 = 0.f, acc1 = 0.f, den = 0.f;
    int j = beg + half;
    for (; j + 6 < end; j += 8) {
        const int s0 = csr_src[j],     s1 = csr_src[j + 2];
        const int s2 = csr_src[j + 4], s3 = csr_src[j + 6];
        const unsigned u0 = h2p[(size_t)s0 * 32 + c];
        const unsigned u1 = h2p[(size_t)s1 * 32 + c];
        const unsigned u2 = h2p[(size_t)s2 * 32 + c];
        const unsigned u3 = h2p[(size_t)s3 * 32 + c];
        const float p0 = __expf(LRELU(es[s0] + edv, 0.2f));
        const float p1 = __expf(LRELU(es[s1] + edv, 0.2f));
        const float p2 = __expf(LRELU(es[s2] + edv, 0.2f));
        const float p3 = __expf(LRELU(es[s3] + edv, 0.2f));
        den += (p0 + p1) + (p2 + p3);
        acc0 = fmaf(p0, bf_lo(u0), fmaf(p1, bf_lo(u1), fmaf(p2, bf_lo(u2), fmaf(p3, bf_lo(u3), acc0))));
        acc1 = fmaf(p0, bf_hi(u0), fmaf(p1, bf_hi(u1), fmaf(p2, bf_hi(u2), fmaf(p3, bf_hi(u3), acc1))));
    }
    for (; j < end; j += 2) {
        const int s = csr_src[j];
        const unsigned u = h2p[(size_t)s * 32 + c];
        const float p = __expf(LRELU(es[s] + edv, 0.2f));
        den += p;
        acc0 = fmaf(p, bf_lo(u), acc0);
        acc1 = fmaf(p, bf_hi(u), acc1);
    }
    den  += __shfl_xor(den, 32);
    acc0 += __shfl_xor(acc0, 32);
    acc1 += __shfl_xor(acc1, 32);
    if (lane < 32) {
        const float2 bb = *(const float2*)&b[c * 2];
        *(float2*)&out[(size_t)n * 64 + c * 2] =
            make_float2(acc0 / den + bb.x, acc1 / den + bb.y);
    }
}

// ---------------------------------------------------------------------------
extern "C" void kernel_launch(void* const* d_in, const int* in_sizes, int n_in,
                              void* d_out, int out_size, void* d_ws, size_t ws_size,
                              hipStream_t stream) {
    const float* x     = (const float*)d_in[0];
    const int*   ei    = (const int*)d_in[1];
    const float* W1    = (const float*)d_in[2];
    const float* asrc1 = (const float*)d_in[3];
    const float* adst1 = (const float*)d_in[4];
    const float* b1    = (const float*)d_in[5];
    const float* W2    = (const float*)d_in[6];
    const float* asrc2 = (const float*)d_in[7];
    const float* adst2 = (const float*)d_in[8];
    const float* b2    = (const float*)d_in[9];
    float* out = (float*)d_out;

    const int N = in_sizes[0] / 128;
    const int E = in_sizes[1] / 2;
    const int Etot = E + N;

    // workspace layout (~83 MB)
    char* p = (char*)d_ws;
    auto alloc = [&](size_t bytes) {
        char* q = p;
        p += (bytes + 255) & ~size_t(255);
        return q;
    };
    unsigned* h1p   = (unsigned*)alloc((size_t)N * 64 * 4);  // bf16x2-packed h1
    unsigned* x2p   = (unsigned*)alloc((size_t)N * 64 * 4);  // bf16x2-packed x2
    unsigned* h2p   = (unsigned*)alloc((size_t)N * 32 * 4);  // bf16x2-packed h2
    float* es1      = (float*)alloc((size_t)N * 4 * 4);
    float* ed1      = (float*)alloc((size_t)N * 4 * 4);
    float* es2      = (float*)alloc((size_t)N * 4);
    float* ed2      = (float*)alloc((size_t)N * 4);
    int*   deg      = (int*)alloc((size_t)N * 4);
    int*   excl     = (int*)alloc((size_t)N * 4);
    int*   bsum     = (int*)alloc(1024);
    int*   rowstart = (int*)alloc((size_t)(N + 1) * 4);
    int*   rank     = (int*)alloc((size_t)E * 4);
    int*   csr_src  = (int*)alloc((size_t)Etot * 4);

    const int ntiles = (N + 63) / 64;
    const int nwb = (N + 3) / 4;            // wave-per-node kernels: 4 waves/block
    const int nchunks = (N + 2047) / 2048;  // <= 64 required (N <= 131072)

    // layer 1 projection + fused scores
    hipMemsetAsync(deg, 0, (size_t)N * 4, stream);
    gemm1_kernel<<<ntiles, 256, 0, stream>>>(x, W1, asrc1, adst1, h1p, es1, ed1, N, ntiles);

    // CSR by destination (shared by both layers)
    rank_count_kernel<<<512, 256, 0, stream>>>(ei, E, deg, rank);
    scan_p1_kernel<<<nchunks, 256, 0, stream>>>(deg, excl, bsum, N);
    scan_p2_kernel<<<1, 64, 0, stream>>>(bsum, nchunks);
    scan_p3_kernel<<<(N + 255) / 256, 256, 0, stream>>>(excl, bsum, rowstart, N, Etot);
    csr_fill_kernel<<<(Etot + 255) / 256, 256, 0, stream>>>(ei, E, N, rowstart, rank, csr_src);

    // layer 1 aggregation (writes bf16x2 leaky_relu(out1+b1) = layer-2 input)
    aggregate1_kernel<<<nwb, 256, 0, stream>>>(h1p, es1, ed1, rowstart, csr_src, b1, x2p, N);

    // layer 2
    gemm2_kernel<<<ntiles, 256, 0, stream>>>(x2p, W2, asrc2, adst2, h2p, es2, ed2, N, ntiles);
    aggregate2_kernel<<<nwb, 256, 0, stream>>>(h2p, es2, ed2, rowstart, csr_src, b2, out, N);
}

// Round 7
// 390.136 us; speedup vs baseline: 5.6679x; 5.6679x over previous
//
#include <hip/hip_runtime.h>
#include <hip/hip_bf16.h>

#define LRELU(v, s) ((v) > 0.0f ? (v) : (s) * (v))

// --- bf16x2 pack/unpack (RNE) ---------------------------------------------
__device__ __forceinline__ unsigned pack_bf16x2(float lo, float hi) {
    unsigned a = __builtin_bit_cast(unsigned, lo);
    unsigned b = __builtin_bit_cast(unsigned, hi);
    a += 0x7fffu + ((a >> 16) & 1u);
    b += 0x7fffu + ((b >> 16) & 1u);
    return (a >> 16) | (b & 0xffff0000u);
}
__device__ __forceinline__ float bf_lo(unsigned u) {
    return __builtin_bit_cast(float, u << 16);
}
__device__ __forceinline__ float bf_hi(unsigned u) {
    return __builtin_bit_cast(float, u & 0xffff0000u);
}

// ---------------------------------------------------------------------------
// GEMM1 + fused scores, ZERO-LDS design.  h1p[N,64(u32)] = bf16x2(x @ W1),
// es/ed[N,4] fp32 from fp32 accumulators.
// Rationale: within a wave the x-operand address depends only on trow
// (2 values/wave, 32 lanes identical -> coalescer merges to 1 txn) and the
// W-operand spans 512B/instr (L2-hot 64KB matrix, streamed via L1).  Per
// kk-group: 8 global b128 loads (~24 L1 cyc) vs 128 FMAs (128 cyc) ->
// VALU-bound.  No LDS, no barriers -> occupancy is VGPR-limited only, so
// cache latency is hidden by TLP instead of hand pipelining (which spilled
// to scratch in the last two rounds).
// 32-row tiles, thread = 4 rows x 4 cols.  N % 32 == 0 here (no tail), but
// rows are clamped for generality.
// ---------------------------------------------------------------------------
__global__ __launch_bounds__(256) void gemm1_kernel(const float* __restrict__ x,
                                                    const float* __restrict__ W,
                                                    const float* __restrict__ asrc,
                                                    const float* __restrict__ adst,
                                                    unsigned* __restrict__ h1p,
                                                    float* __restrict__ es,
                                                    float* __restrict__ ed,
                                                    int N, int ntiles) {
    const int tid = threadIdx.x;
    const int jq = tid & 31;    // col quad -> cols 4jq..4jq+3 (head = jq>>3)
    const int trow = tid >> 5;  // row group 0..7 -> rows trow*4..trow*4+3
    const float4 asv = *(const float4*)&asrc[jq * 4];
    const float4 adv = *(const float4*)&adst[jq * 4];

    for (int tile = blockIdx.x; tile < ntiles; tile += gridDim.x) {
        const int row0 = tile * 32 + trow * 4;
        int rows[4];
#pragma unroll
        for (int r = 0; r < 4; ++r) rows[r] = min(row0 + r, N - 1);

        float acc[4][4] = {};
#pragma unroll 2
        for (int kk = 0; kk < 128; kk += 4) {
            const float4 w0 = *(const float4*)&W[(size_t)(kk + 0) * 128 + jq * 4];
            const float4 w1 = *(const float4*)&W[(size_t)(kk + 1) * 128 + jq * 4];
            const float4 w2 = *(const float4*)&W[(size_t)(kk + 2) * 128 + jq * 4];
            const float4 w3 = *(const float4*)&W[(size_t)(kk + 3) * 128 + jq * 4];
#pragma unroll
            for (int r = 0; r < 4; ++r) {
                const float4 xv = *(const float4*)&x[(size_t)rows[r] * 128 + kk];
                acc[r][0] = fmaf(xv.x, w0.x, fmaf(xv.y, w1.x, fmaf(xv.z, w2.x, fmaf(xv.w, w3.x, acc[r][0]))));
                acc[r][1] = fmaf(xv.x, w0.y, fmaf(xv.y, w1.y, fmaf(xv.z, w2.y, fmaf(xv.w, w3.y, acc[r][1]))));
                acc[r][2] = fmaf(xv.x, w0.z, fmaf(xv.y, w1.z, fmaf(xv.z, w2.z, fmaf(xv.w, w3.z, acc[r][2]))));
                acc[r][3] = fmaf(xv.x, w0.w, fmaf(xv.y, w1.w, fmaf(xv.z, w2.w, fmaf(xv.w, w3.w, acc[r][3]))));
            }
        }
        // ---- epilogue: fused scores (fp32-exact) + bf16x2 pack ----
#pragma unroll
        for (int r = 0; r < 4; ++r) {
            const int row = row0 + r;
            float ps = acc[r][0] * asv.x + acc[r][1] * asv.y + acc[r][2] * asv.z + acc[r][3] * asv.w;
            float pd = acc[r][0] * adv.x + acc[r][1] * adv.y + acc[r][2] * adv.z + acc[r][3] * adv.w;
#pragma unroll
            for (int off = 1; off <= 4; off <<= 1) {
                ps += __shfl_xor(ps, off);
                pd += __shfl_xor(pd, off);
            }
            if (row < N) {
                if ((jq & 7) == 0) {
                    es[row * 4 + (jq >> 3)] = ps;
                    ed[row * 4 + (jq >> 3)] = pd;
                }
                *(uint2*)&h1p[(size_t)row * 64 + jq * 2] =
                    make_uint2(pack_bf16x2(acc[r][0], acc[r][1]),
                               pack_bf16x2(acc[r][2], acc[r][3]));
            }
        }
    }
}

// ---------------------------------------------------------------------------
// GEMM2 + fused scores, same ZERO-LDS design.  h2p[N,32(u32)] =
// bf16x2(x2 @ W2), es2/ed2[N] fp32.  x2 arrives bf16x2-packed; unpacked
// in-register (uint2 = 4 k-values).  64-row tiles, thread = 4 rows x 4 cols.
// ---------------------------------------------------------------------------
__global__ __launch_bounds__(256) void gemm2_kernel(const unsigned* __restrict__ x2p,
                                                    const float* __restrict__ W,
                                                    const float* __restrict__ asrc,
                                                    const float* __restrict__ adst,
                                                    unsigned* __restrict__ h2p,
                                                    float* __restrict__ es,
                                                    float* __restrict__ ed,
                                                    int N, int ntiles) {
    const int tid = threadIdx.x;
    const int cg = tid & 15;    // col quad -> cols 4cg..4cg+3
    const int trow = tid >> 4;  // row group 0..15 -> rows trow*4..trow*4+3
    const float4 asv = *(const float4*)&asrc[cg * 4];
    const float4 adv = *(const float4*)&adst[cg * 4];

    for (int tile = blockIdx.x; tile < ntiles; tile += gridDim.x) {
        const int row0 = tile * 64 + trow * 4;
        int rows[4];
#pragma unroll
        for (int r = 0; r < 4; ++r) rows[r] = min(row0 + r, N - 1);

        float acc[4][4] = {};
#pragma unroll 2
        for (int kk = 0; kk < 128; kk += 4) {
            const float4 w0 = *(const float4*)&W[(size_t)(kk + 0) * 64 + cg * 4];
            const float4 w1 = *(const float4*)&W[(size_t)(kk + 1) * 64 + cg * 4];
            const float4 w2 = *(const float4*)&W[(size_t)(kk + 2) * 64 + cg * 4];
            const float4 w3 = *(const float4*)&W[(size_t)(kk + 3) * 64 + cg * 4];
#pragma unroll
            for (int r = 0; r < 4; ++r) {
                const uint2 u = *(const uint2*)&x2p[(size_t)rows[r] * 64 + (kk >> 1)];
                const float xv0 = bf_lo(u.x), xv1 = bf_hi(u.x);
                const float xv2 = bf_lo(u.y), xv3 = bf_hi(u.y);
                acc[r][0] = fmaf(xv0, w0.x, fmaf(xv1, w1.x, fmaf(xv2, w2.x, fmaf(xv3, w3.x, acc[r][0]))));
                acc[r][1] = fmaf(xv0, w0.y, fmaf(xv1, w1.y, fmaf(xv2, w2.y, fmaf(xv3, w3.y, acc[r][1]))));
                acc[r][2] = fmaf(xv0, w0.z, fmaf(xv1, w1.z, fmaf(xv2, w2.z, fmaf(xv3, w3.z, acc[r][2]))));
                acc[r][3] = fmaf(xv0, w0.w, fmaf(xv1, w1.w, fmaf(xv2, w2.w, fmaf(xv3, w3.w, acc[r][3]))));
            }
        }
#pragma unroll
        for (int r = 0; r < 4; ++r) {
            const int row = row0 + r;
            float ps = acc[r][0] * asv.x + acc[r][1] * asv.y + acc[r][2] * asv.z + acc[r][3] * asv.w;
            float pd = acc[r][0] * adv.x + acc[r][1] * adv.y + acc[r][2] * adv.z + acc[r][3] * adv.w;
#pragma unroll
            for (int off = 1; off <= 8; off <<= 1) {
                ps += __shfl_xor(ps, off);
                pd += __shfl_xor(pd, off);
            }
            if (row < N) {
                if (cg == 0) { es[row] = ps; ed[row] = pd; }
                *(uint2*)&h2p[(size_t)row * 32 + cg * 2] =
                    make_uint2(pack_bf16x2(acc[r][0], acc[r][1]),
                               pack_bf16x2(acc[r][2], acc[r][3]));
            }
        }
    }
}

// ---------------------------------------------------------------------------
// rank_count: one returning atomic per edge, MLP-pipelined — 4 independent
// atomics in flight per thread (manual unroll over grid-stride offsets).
// ---------------------------------------------------------------------------
__global__ __launch_bounds__(256) void rank_count_kernel(const int* __restrict__ ei, int E,
                                                         int* __restrict__ deg,
                                                         int* __restrict__ rank) {
    const int stride = gridDim.x * 256;
    int e = blockIdx.x * 256 + threadIdx.x;
    for (; e + 3 * stride < E; e += 4 * stride) {
        const int d0 = ei[E + e];
        const int d1 = ei[E + e + stride];
        const int d2 = ei[E + e + 2 * stride];
        const int d3 = ei[E + e + 3 * stride];
        const int r0 = atomicAdd(&deg[d0], 1);
        const int r1 = atomicAdd(&deg[d1], 1);
        const int r2 = atomicAdd(&deg[d2], 1);
        const int r3 = atomicAdd(&deg[d3], 1);
        rank[e] = r0;
        rank[e + stride] = r1;
        rank[e + 2 * stride] = r2;
        rank[e + 3 * stride] = r3;
    }
    for (; e < E; e += stride)
        rank[e] = atomicAdd(&deg[ei[E + e]], 1);
}

// ---------------------------------------------------------------------------
// CSR build: scan of (deg+1), then atomic-free fill; self-loop takes the
// deterministic LAST slot per segment.
// ---------------------------------------------------------------------------
__global__ __launch_bounds__(256) void scan_p1_kernel(const int* __restrict__ deg,
                                                      int* __restrict__ excl,
                                                      int* __restrict__ bsum, int N) {
    __shared__ int lds[256];
    const int tid = threadIdx.x;
    const int base = blockIdx.x * 2048;
    const int idx0 = base + tid * 8;
    int v[8];
    int s = 0;
#pragma unroll
    for (int i = 0; i < 8; ++i) {
        v[i] = (idx0 + i < N) ? deg[idx0 + i] + 1 : 0;  // +1 = self-loop
        s += v[i];
    }
    lds[tid] = s;
    __syncthreads();
    for (int off = 1; off < 256; off <<= 1) {
        int t = (tid >= off) ? lds[tid - off] : 0;
        __syncthreads();
        lds[tid] += t;
        __syncthreads();
    }
    const int texcl = lds[tid] - s;
    if (tid == 255) bsum[blockIdx.x] = lds[255];
    int run = texcl;
#pragma unroll
    for (int i = 0; i < 8; ++i) {
        if (idx0 + i < N) excl[idx0 + i] = run;
        run += v[i];
    }
}

__global__ void scan_p2_kernel(int* __restrict__ bsum, int nchunks) {
    const int lane = threadIdx.x;
    int v = (lane < nchunks) ? bsum[lane] : 0;
    const int orig = v;
#pragma unroll
    for (int off = 1; off < 64; off <<= 1) {
        int t = __shfl_up(v, off);
        if (lane >= off) v += t;
    }
    if (lane < nchunks) bsum[lane] = v - orig;
}

__global__ void scan_p3_kernel(const int* __restrict__ excl, const int* __restrict__ bsum,
                               int* __restrict__ rowstart, int N, int Etot) {
    const int i = blockIdx.x * 256 + threadIdx.x;
    if (i < N) rowstart[i] = excl[i] + bsum[i >> 11];
    if (i == 0) rowstart[N] = Etot;
}

__global__ void csr_fill_kernel(const int* __restrict__ ei, int E, int N,
                                const int* __restrict__ rowstart,
                                const int* __restrict__ rank,
                                int* __restrict__ csr_src) {
    const int e = blockIdx.x * 256 + threadIdx.x;
    if (e < E) {
        const int d = ei[E + e];
        csr_src[rowstart[d] + rank[e]] = ei[e];
    } else if (e < E + N) {
        const int d = e - E;
        csr_src[rowstart[d + 1] - 1] = d;
    }
}

// ---------------------------------------------------------------------------
// Aggregation layer 1: wave per dst node; lane covers channels {2l, 2l+1}
// (both in head l>>4 -> ONE exp per lane per edge). Single pass (logits
// bounded, fp32 exp exact for softmax ratio), 4-edge unroll. bf16x2 gather.
// ---------------------------------------------------------------------------
__global__ __launch_bounds__(256) void aggregate1_kernel(const unsigned* __restrict__ h1p,
                                                         const float* __restrict__ es,
                                                         const float* __restrict__ ed,
                                                         const int* __restrict__ rowstart,
                                                         const int* __restrict__ csr_src,
                                                         const float* __restrict__ b,
                                                         unsigned* __restrict__ x2p, int N) {
    const int n = (blockIdx.x * 256 + threadIdx.x) >> 6;
    const int lane = threadIdx.x & 63;
    if (n >= N) return;
    const int hh = lane >> 4;  // head 0..3
    const float edv = ed[n * 4 + hh];
    const int beg = rowstart[n], end = rowstart[n + 1];

    float acc0 = 0.f, acc1 = 0.f, den = 0.f;
    int j = beg;
    const int end4 = beg + ((end - beg) & ~3);
    for (; j < end4; j += 4) {
        const int s0 = csr_src[j], s1 = csr_src[j + 1];
        const int s2 = csr_src[j + 2], s3 = csr_src[j + 3];
        const unsigned u0 = h1p[(size_t)s0 * 64 + lane];
        const unsigned u1 = h1p[(size_t)s1 * 64 + lane];
        const unsigned u2 = h1p[(size_t)s2 * 64 + lane];
        const unsigned u3 = h1p[(size_t)s3 * 64 + lane];
        const float e0 = es[s0 * 4 + hh], e1 = es[s1 * 4 + hh];
        const float e2 = es[s2 * 4 + hh], e3 = es[s3 * 4 + hh];
        const float p0 = __expf(LRELU(e0 + edv, 0.2f));
        const float p1 = __expf(LRELU(e1 + edv, 0.2f));
        const float p2 = __expf(LRELU(e2 + edv, 0.2f));
        const float p3 = __expf(LRELU(e3 + edv, 0.2f));
        den += (p0 + p1) + (p2 + p3);
        acc0 = fmaf(p0, bf_lo(u0), fmaf(p1, bf_lo(u1), fmaf(p2, bf_lo(u2), fmaf(p3, bf_lo(u3), acc0))));
        acc1 = fmaf(p0, bf_hi(u0), fmaf(p1, bf_hi(u1), fmaf(p2, bf_hi(u2), fmaf(p3, bf_hi(u3), acc1))));
    }
    for (; j < end; ++j) {
        const int s = csr_src[j];
        const unsigned u = h1p[(size_t)s * 64 + lane];
        const float p = __expf(LRELU(es[s * 4 + hh] + edv, 0.2f));
        den += p;
        acc0 = fmaf(p, bf_lo(u), acc0);
        acc1 = fmaf(p, bf_hi(u), acc1);
    }
    const float2 bb = *(const float2*)&b[lane * 2];
    float o0 = acc0 / den + bb.x;  o0 = LRELU(o0, 0.01f);
    float o1 = acc1 / den + bb.y;  o1 = LRELU(o1, 0.01f);
    x2p[(size_t)n * 64 + lane] = pack_bf16x2(o0, o1);
}

// ---------------------------------------------------------------------------
// Aggregation layer 2: wave per dst node, TWO edges in flight per iteration
// (half-wave each; lane covers channels {2c, 2c+1}); unroll-4 -> 8 edges.
// ---------------------------------------------------------------------------
__global__ __launch_bounds__(256) void aggregate2_kernel(const unsigned* __restrict__ h2p,
                                                         const float* __restrict__ es,
                                                         const float* __restrict__ ed,
                                                         const int* __restrict__ rowstart,
                                                         const int* __restrict__ csr_src,
                                                         const float* __restrict__ b,
                                                         float* __restrict__ out, int N) {
    const int n = (blockIdx.x * 256 + threadIdx.x) >> 6;
    const int lane = threadIdx.x & 63;
    if (n >= N) return;
    const int half = lane >> 5, c = lane & 31;
    const float edv = ed[n];
    const int beg = rowstart[n], end = rowstart[n + 1];

    float acc0 = 0.f, acc1 = 0.f, den = 0.f;
    int j = beg + half;
    for (; j + 6 < end; j += 8) {
        const int s0 = csr_src[j],     s1 = csr_src[j + 2];
        const int s2 = csr_src[j + 4], s3 = csr_src[j + 6];
        const unsigned u0 = h2p[(size_t)s0 * 32 + c];
        const unsigned u1 = h2p[(size_t)s1 * 32 + c];
        const unsigned u2 = h2p[(size_t)s2 * 32 + c];
        const unsigned u3 = h2p[(size_t)s3 * 32 + c];
        const float p0 = __expf(LRELU(es[s0] + edv, 0.2f));
        const float p1 = __expf(LRELU(es[s1] + edv, 0.2f));
        const float p2 = __expf(LRELU(es[s2] + edv, 0.2f));
        const float p3 = __expf(LRELU(es[s3] + edv, 0.2f));
        den += (p0 + p1) + (p2 + p3);
        acc0 = fmaf(p0, bf_lo(u0), fmaf(p1, bf_lo(u1), fmaf(p2, bf_lo(u2), fmaf(p3, bf_lo(u3), acc0))));
        acc1 = fmaf(p0, bf_hi(u0), fmaf(p1, bf_hi(u1), fmaf(p2, bf_hi(u2), fmaf(p3, bf_hi(u3), acc1))));
    }
    for (; j < end; j += 2) {
        const int s = csr_src[j];
        const unsigned u = h2p[(size_t)s * 32 + c];
        const float p = __expf(LRELU(es[s] + edv, 0.2f));
        den += p;
        acc0 = fmaf(p, bf_lo(u), acc0);
        acc1 = fmaf(p, bf_hi(u), acc1);
    }
    den  += __shfl_xor(den, 32);
    acc0 += __shfl_xor(acc0, 32);
    acc1 += __shfl_xor(acc1, 32);
    if (lane < 32) {
        const float2 bb = *(const float2*)&b[c * 2];
        *(float2*)&out[(size_t)n * 64 + c * 2] =
            make_float2(acc0 / den + bb.x, acc1 / den + bb.y);
    }
}

// ---------------------------------------------------------------------------
extern "C" void kernel_launch(void* const* d_in, const int* in_sizes, int n_in,
                              void* d_out, int out_size, void* d_ws, size_t ws_size,
                              hipStream_t stream) {
    const float* x     = (const float*)d_in[0];
    const int*   ei    = (const int*)d_in[1];
    const float* W1    = (const float*)d_in[2];
    const float* asrc1 = (const float*)d_in[3];
    const float* adst1 = (const float*)d_in[4];
    const float* b1    = (const float*)d_in[5];
    const float* W2    = (const float*)d_in[6];
    const float* asrc2 = (const float*)d_in[7];
    const float* adst2 = (const float*)d_in[8];
    const float* b2    = (const float*)d_in[9];
    float* out = (float*)d_out;

    const int N = in_sizes[0] / 128;
    const int E = in_sizes[1] / 2;
    const int Etot = E + N;

    // workspace layout (~83 MB)
    char* p = (char*)d_ws;
    auto alloc = [&](size_t bytes) {
        char* q = p;
        p += (bytes + 255) & ~size_t(255);
        return q;
    };
    unsigned* h1p   = (unsigned*)alloc((size_t)N * 64 * 4);  // bf16x2-packed h1
    unsigned* x2p   = (unsigned*)alloc((size_t)N * 64 * 4);  // bf16x2-packed x2
    unsigned* h2p   = (unsigned*)alloc((size_t)N * 32 * 4);  // bf16x2-packed h2
    float* es1      = (float*)alloc((size_t)N * 4 * 4);
    float* ed1      = (float*)alloc((size_t)N * 4 * 4);
    float* es2      = (float*)alloc((size_t)N * 4);
    float* ed2      = (float*)alloc((size_t)N * 4);
    int*   deg      = (int*)alloc((size_t)N * 4);
    int*   excl     = (int*)alloc((size_t)N * 4);
    int*   bsum     = (int*)alloc(1024);
    int*   rowstart = (int*)alloc((size_t)(N + 1) * 4);
    int*   rank     = (int*)alloc((size_t)E * 4);
    int*   csr_src  = (int*)alloc((size_t)Etot * 4);

    const int ntiles1 = (N + 31) / 32;
    const int ntiles2 = (N + 63) / 64;
    const int nwb = (N + 3) / 4;            // wave-per-node kernels: 4 waves/block
    const int nchunks = (N + 2047) / 2048;  // <= 64 required (N <= 131072)

    // layer 1 projection + fused scores
    hipMemsetAsync(deg, 0, (size_t)N * 4, stream);
    gemm1_kernel<<<ntiles1, 256, 0, stream>>>(x, W1, asrc1, adst1, h1p, es1, ed1, N, ntiles1);

    // CSR by destination (shared by both layers)
    rank_count_kernel<<<512, 256, 0, stream>>>(ei, E, deg, rank);
    scan_p1_kernel<<<nchunks, 256, 0, stream>>>(deg, excl, bsum, N);
    scan_p2_kernel<<<1, 64, 0, stream>>>(bsum, nchunks);
    scan_p3_kernel<<<(N + 255) / 256, 256, 0, stream>>>(excl, bsum, rowstart, N, Etot);
    csr_fill_kernel<<<(Etot + 255) / 256, 256, 0, stream>>>(ei, E, N, rowstart, rank, csr_src);

    // layer 1 aggregation (writes bf16x2 leaky_relu(out1+b1) = layer-2 input)
    aggregate1_kernel<<<nwb, 256, 0, stream>>>(h1p, es1, ed1, rowstart, csr_src, b1, x2p, N);

    // layer 2
    gemm2_kernel<<<ntiles2, 256, 0, stream>>>(x2p, W2, asrc2, adst2, h2p, es2, ed2, N, ntiles2);
    aggregate2_kernel<<<nwb, 256, 0, stream>>>(h2p, es2, ed2, rowstart, csr_src, b2, out, N);
}

// Round 8
// 304.182 us; speedup vs baseline: 7.2695x; 1.2826x over previous
//
#include <hip/hip_runtime.h>
#include <hip/hip_bf16.h>

#define LRELU(v, s) ((v) > 0.0f ? (v) : (s) * (v))

typedef short bf16x8 __attribute__((ext_vector_type(8)));
typedef float f32x4 __attribute__((ext_vector_type(4)));

// --- bf16 pack helpers (RNE) ----------------------------------------------
__device__ __forceinline__ unsigned pack_bf16x2(float lo, float hi) {
    unsigned a = __builtin_bit_cast(unsigned, lo);
    unsigned b = __builtin_bit_cast(unsigned, hi);
    a += 0x7fffu + ((a >> 16) & 1u);
    b += 0x7fffu + ((b >> 16) & 1u);
    return (a >> 16) | (b & 0xffff0000u);
}
__device__ __forceinline__ unsigned short bf16r(float f) {
    unsigned a = __builtin_bit_cast(unsigned, f);
    a += 0x7fffu + ((a >> 16) & 1u);
    return (unsigned short)(a >> 16);
}
__device__ __forceinline__ float bf_lo(unsigned u) {
    return __builtin_bit_cast(float, u << 16);
}
__device__ __forceinline__ float bf_hi(unsigned u) {
    return __builtin_bit_cast(float, u & 0xffff0000u);
}

// ---------------------------------------------------------------------------
// prep: pack W1/W2 into MFMA-B frag-linear bf16 layout.
// Frag for (ct,kt,lane): element i = W[8*(lane>>4)+32*kt+i][ct*16+(lane&15)],
// stored at Wb[(ct*4+kt)*64+lane] as 4 u32 (8 bf16) -> coalesced uint4 loads.
// Wb1: ct=0..7 (2048 frags), Wb2: ct=0..3 (1024 frags).
// ---------------------------------------------------------------------------
__global__ void prep_kernel(const float* __restrict__ W1, const float* __restrict__ W2,
                            unsigned* __restrict__ Wb1, unsigned* __restrict__ Wb2) {
    const int t = blockIdx.x * 256 + threadIdx.x;
    if (t < 2048) {
        const int lane = t & 63, kt = (t >> 6) & 3, ct = t >> 8;
        const int col = ct * 16 + (lane & 15);
        const int kb = 8 * (lane >> 4) + 32 * kt;
        uint4 u;
        u.x = pack_bf16x2(W1[(size_t)(kb + 0) * 128 + col], W1[(size_t)(kb + 1) * 128 + col]);
        u.y = pack_bf16x2(W1[(size_t)(kb + 2) * 128 + col], W1[(size_t)(kb + 3) * 128 + col]);
        u.z = pack_bf16x2(W1[(size_t)(kb + 4) * 128 + col], W1[(size_t)(kb + 5) * 128 + col]);
        u.w = pack_bf16x2(W1[(size_t)(kb + 6) * 128 + col], W1[(size_t)(kb + 7) * 128 + col]);
        *(uint4*)&Wb1[t * 4] = u;
    } else if (t < 3072) {
        const int s = t - 2048;
        const int lane = s & 63, kt = (s >> 6) & 3, ct = s >> 8;
        const int col = ct * 16 + (lane & 15);
        const int kb = 8 * (lane >> 4) + 32 * kt;
        uint4 u;
        u.x = pack_bf16x2(W2[(size_t)(kb + 0) * 64 + col], W2[(size_t)(kb + 1) * 64 + col]);
        u.y = pack_bf16x2(W2[(size_t)(kb + 2) * 64 + col], W2[(size_t)(kb + 3) * 64 + col]);
        u.z = pack_bf16x2(W2[(size_t)(kb + 4) * 64 + col], W2[(size_t)(kb + 5) * 64 + col]);
        u.w = pack_bf16x2(W2[(size_t)(kb + 6) * 64 + col], W2[(size_t)(kb + 7) * 64 + col]);
        *(uint4*)&Wb2[s * 4] = u;
    }
}

// ---------------------------------------------------------------------------
// GEMM1, MFMA: h1[N][128] bf16 = bf16(x) @ bf16(W1).  Wave = 16 rows.
// A frag (16x32): row = lane&15, k = 8*(lane>>4)+i — loaded as fp32 and
// packed in-register.  B from frag-linear Wb1 (coalesced uint4).  D layout:
// col = lane&15, row = (lane>>4)*4+reg (m89-verified).  No LDS, no barriers.
// ---------------------------------------------------------------------------
__global__ __launch_bounds__(256) void gemm1_kernel(const float* __restrict__ x,
                                                    const unsigned* __restrict__ Wb1,
                                                    unsigned short* __restrict__ h1,
                                                    int N) {
    const int wid = threadIdx.x >> 6, lane = threadIdx.x & 63;
    const int row0 = (blockIdx.x * 4 + wid) * 16;
    if (row0 >= N) return;
    const int g = lane >> 4;
    const int mrow = min(row0 + (lane & 15), N - 1);

    bf16x8 afrag[4];
#pragma unroll
    for (int kt = 0; kt < 4; ++kt) {
        const float4 v0 = *(const float4*)&x[(size_t)mrow * 128 + g * 8 + kt * 32];
        const float4 v1 = *(const float4*)&x[(size_t)mrow * 128 + g * 8 + kt * 32 + 4];
        uint4 u;
        u.x = pack_bf16x2(v0.x, v0.y);
        u.y = pack_bf16x2(v0.z, v0.w);
        u.z = pack_bf16x2(v1.x, v1.y);
        u.w = pack_bf16x2(v1.z, v1.w);
        afrag[kt] = __builtin_bit_cast(bf16x8, u);
    }
#pragma unroll
    for (int ct = 0; ct < 8; ++ct) {
        f32x4 acc = {0.f, 0.f, 0.f, 0.f};
#pragma unroll
        for (int kt = 0; kt < 4; ++kt) {
            const bf16x8 b = __builtin_bit_cast(bf16x8, *(const uint4*)&Wb1[((ct * 4 + kt) * 64 + lane) * 4]);
            acc = __builtin_amdgcn_mfma_f32_16x16x32_bf16(afrag[kt], b, acc, 0, 0, 0);
        }
        const int col = ct * 16 + (lane & 15);
#pragma unroll
        for (int r = 0; r < 4; ++r) {
            const int row = row0 + g * 4 + r;
            if (row < N) h1[(size_t)row * 128 + col] = bf16r(acc[r]);
        }
    }
}

// ---------------------------------------------------------------------------
// GEMM2, MFMA: h2[N][64] bf16 = x2(bf16) @ bf16(W2).  x2p's bf16x2 row-major
// layout IS the A-frag layout -> direct uint4 bit_cast, no conversion.
// ---------------------------------------------------------------------------
__global__ __launch_bounds__(256) void gemm2_kernel(const unsigned* __restrict__ x2p,
                                                    const unsigned* __restrict__ Wb2,
                                                    unsigned short* __restrict__ h2,
                                                    int N) {
    const int wid = threadIdx.x >> 6, lane = threadIdx.x & 63;
    const int row0 = (blockIdx.x * 4 + wid) * 16;
    if (row0 >= N) return;
    const int g = lane >> 4;
    const int mrow = min(row0 + (lane & 15), N - 1);

    bf16x8 afrag[4];
#pragma unroll
    for (int kt = 0; kt < 4; ++kt)
        afrag[kt] = __builtin_bit_cast(bf16x8, *(const uint4*)&x2p[(size_t)mrow * 64 + g * 4 + kt * 16]);
#pragma unroll
    for (int ct = 0; ct < 4; ++ct) {
        f32x4 acc = {0.f, 0.f, 0.f, 0.f};
#pragma unroll
        for (int kt = 0; kt < 4; ++kt) {
            const bf16x8 b = __builtin_bit_cast(bf16x8, *(const uint4*)&Wb2[((ct * 4 + kt) * 64 + lane) * 4]);
            acc = __builtin_amdgcn_mfma_f32_16x16x32_bf16(afrag[kt], b, acc, 0, 0, 0);
        }
        const int col = ct * 16 + (lane & 15);
#pragma unroll
        for (int r = 0; r < 4; ++r) {
            const int row = row0 + g * 4 + r;
            if (row < N) h2[(size_t)row * 64 + col] = bf16r(acc[r]);
        }
    }
}

// ---------------------------------------------------------------------------
// Scores layer 1: es/ed[n][h] = h1[n] . a (per 32-ch head).  Wave per node;
// lane covers channels {2l,2l+1} (head = l>>4); 4-shfl reduce per head group.
// ---------------------------------------------------------------------------
__global__ __launch_bounds__(256) void escore1_kernel(const unsigned* __restrict__ h1u,
                                                      const float* __restrict__ asrc,
                                                      const float* __restrict__ adst,
                                                      float* __restrict__ es,
                                                      float* __restrict__ ed, int N) {
    const int n = (blockIdx.x * 256 + threadIdx.x) >> 6;
    const int lane = threadIdx.x & 63;
    if (n >= N) return;
    const unsigned u = h1u[(size_t)n * 64 + lane];
    const float lo = bf_lo(u), hi = bf_hi(u);
    float s = lo * asrc[2 * lane] + hi * asrc[2 * lane + 1];
    float d = lo * adst[2 * lane] + hi * adst[2 * lane + 1];
#pragma unroll
    for (int off = 1; off <= 8; off <<= 1) {
        s += __shfl_xor(s, off);
        d += __shfl_xor(d, off);
    }
    if ((lane & 15) == 0) {
        es[n * 4 + (lane >> 4)] = s;
        ed[n * 4 + (lane >> 4)] = d;
    }
}

// Scores layer 2: single head over 64 ch; TWO nodes per wave (32 lanes each).
__global__ __launch_bounds__(256) void escore2_kernel(const unsigned* __restrict__ h2u,
                                                      const float* __restrict__ asrc,
                                                      const float* __restrict__ adst,
                                                      float* __restrict__ es,
                                                      float* __restrict__ ed, int N) {
    const int lane = threadIdx.x & 63;
    const int n = ((blockIdx.x * 256 + threadIdx.x) >> 6) * 2 + (lane >> 5);
    if (n >= N) return;
    const int c = lane & 31;
    const unsigned u = h2u[(size_t)n * 32 + c];
    const float lo = bf_lo(u), hi = bf_hi(u);
    float s = lo * asrc[2 * c] + hi * asrc[2 * c + 1];
    float d = lo * adst[2 * c] + hi * adst[2 * c + 1];
#pragma unroll
    for (int off = 1; off <= 16; off <<= 1) {
        s += __shfl_xor(s, off);
        d += __shfl_xor(d, off);
    }
    if (c == 0) { es[n] = s; ed[n] = d; }
}

// ---------------------------------------------------------------------------
// rank_count: one returning atomic per edge, 4 independent atomics in flight.
// ---------------------------------------------------------------------------
__global__ __launch_bounds__(256) void rank_count_kernel(const int* __restrict__ ei, int E,
                                                         int* __restrict__ deg,
                                                         int* __restrict__ rank) {
    const int stride = gridDim.x * 256;
    int e = blockIdx.x * 256 + threadIdx.x;
    for (; e + 3 * stride < E; e += 4 * stride) {
        const int d0 = ei[E + e];
        const int d1 = ei[E + e + stride];
        const int d2 = ei[E + e + 2 * stride];
        const int d3 = ei[E + e + 3 * stride];
        const int r0 = atomicAdd(&deg[d0], 1);
        const int r1 = atomicAdd(&deg[d1], 1);
        const int r2 = atomicAdd(&deg[d2], 1);
        const int r3 = atomicAdd(&deg[d3], 1);
        rank[e] = r0;
        rank[e + stride] = r1;
        rank[e + 2 * stride] = r2;
        rank[e + 3 * stride] = r3;
    }
    for (; e < E; e += stride)
        rank[e] = atomicAdd(&deg[ei[E + e]], 1);
}

// ---------------------------------------------------------------------------
// CSR build: scan of (deg+1), atomic-free fill; self-loop takes LAST slot.
// ---------------------------------------------------------------------------
__global__ __launch_bounds__(256) void scan_p1_kernel(const int* __restrict__ deg,
                                                      int* __restrict__ excl,
                                                      int* __restrict__ bsum, int N) {
    __shared__ int lds[256];
    const int tid = threadIdx.x;
    const int base = blockIdx.x * 2048;
    const int idx0 = base + tid * 8;
    int v[8];
    int s = 0;
#pragma unroll
    for (int i = 0; i < 8; ++i) {
        v[i] = (idx0 + i < N) ? deg[idx0 + i] + 1 : 0;  // +1 = self-loop
        s += v[i];
    }
    lds[tid] = s;
    __syncthreads();
    for (int off = 1; off < 256; off <<= 1) {
        int t = (tid >= off) ? lds[tid - off] : 0;
        __syncthreads();
        lds[tid] += t;
        __syncthreads();
    }
    const int texcl = lds[tid] - s;
    if (tid == 255) bsum[blockIdx.x] = lds[255];
    int run = texcl;
#pragma unroll
    for (int i = 0; i < 8; ++i) {
        if (idx0 + i < N) excl[idx0 + i] = run;
        run += v[i];
    }
}

__global__ void scan_p2_kernel(int* __restrict__ bsum, int nchunks) {
    const int lane = threadIdx.x;
    int v = (lane < nchunks) ? bsum[lane] : 0;
    const int orig = v;
#pragma unroll
    for (int off = 1; off < 64; off <<= 1) {
        int t = __shfl_up(v, off);
        if (lane >= off) v += t;
    }
    if (lane < nchunks) bsum[lane] = v - orig;
}

__global__ void scan_p3_kernel(const int* __restrict__ excl, const int* __restrict__ bsum,
                               int* __restrict__ rowstart, int N, int Etot) {
    const int i = blockIdx.x * 256 + threadIdx.x;
    if (i < N) rowstart[i] = excl[i] + bsum[i >> 11];
    if (i == 0) rowstart[N] = Etot;
}

__global__ void csr_fill_kernel(const int* __restrict__ ei, int E, int N,
                                const int* __restrict__ rowstart,
                                const int* __restrict__ rank,
                                int* __restrict__ csr_src) {
    const int e = blockIdx.x * 256 + threadIdx.x;
    if (e < E) {
        const int d = ei[E + e];
        csr_src[rowstart[d] + rank[e]] = ei[e];
    } else if (e < E + N) {
        const int d = e - E;
        csr_src[rowstart[d + 1] - 1] = d;
    }
}

// ---------------------------------------------------------------------------
// Aggregation layer 1: wave per dst node; lane covers channels {2l, 2l+1}
// (head = l>>4, ONE exp per lane per edge).  Single pass, 4-edge unroll.
// ---------------------------------------------------------------------------
__global__ __launch_bounds__(256) void aggregate1_kernel(const unsigned* __restrict__ h1p,
                                                         const float* __restrict__ es,
                                                         const float* __restrict__ ed,
                                                         const int* __restrict__ rowstart,
                                                         const int* __restrict__ csr_src,
                                                         const float* __restrict__ b,
                                                         unsigned* __restrict__ x2p, int N) {
    const int n = (blockIdx.x * 256 + threadIdx.x) >> 6;
    const int lane = threadIdx.x & 63;
    if (n >= N) return;
    const int hh = lane >> 4;  // head 0..3
    const float edv = ed[n * 4 + hh];
    const int beg = rowstart[n], end = rowstart[n + 1];

    float acc0 = 0.f, acc1 = 0.f, den = 0.f;
    int j = beg;
    const int end4 = beg + ((end - beg) & ~3);
    for (; j < end4; j += 4) {
        const int s0 = csr_src[j], s1 = csr_src[j + 1];
        const int s2 = csr_src[j + 2], s3 = csr_src[j + 3];
        const unsigned u0 = h1p[(size_t)s0 * 64 + lane];
        const unsigned u1 = h1p[(size_t)s1 * 64 + lane];
        const unsigned u2 = h1p[(size_t)s2 * 64 + lane];
        const unsigned u3 = h1p[(size_t)s3 * 64 + lane];
        const float e0 = es[s0 * 4 + hh], e1 = es[s1 * 4 + hh];
        const float e2 = es[s2 * 4 + hh], e3 = es[s3 * 4 + hh];
        const float p0 = __expf(LRELU(e0 + edv, 0.2f));
        const float p1 = __expf(LRELU(e1 + edv, 0.2f));
        const float p2 = __expf(LRELU(e2 + edv, 0.2f));
        const float p3 = __expf(LRELU(e3 + edv, 0.2f));
        den += (p0 + p1) + (p2 + p3);
        acc0 = fmaf(p0, bf_lo(u0), fmaf(p1, bf_lo(u1), fmaf(p2, bf_lo(u2), fmaf(p3, bf_lo(u3), acc0))));
        acc1 = fmaf(p0, bf_hi(u0), fmaf(p1, bf_hi(u1), fmaf(p2, bf_hi(u2), fmaf(p3, bf_hi(u3), acc1))));
    }
    for (; j < end; ++j) {
        const int s = csr_src[j];
        const unsigned u = h1p[(size_t)s * 64 + lane];
        const float p = __expf(LRELU(es[s * 4 + hh] + edv, 0.2f));
        den += p;
        acc0 = fmaf(p, bf_lo(u), acc0);
        acc1 = fmaf(p, bf_hi(u), acc1);
    }
    const float2 bb = *(const float2*)&b[lane * 2];
    float o0 = acc0 / den + bb.x;  o0 = LRELU(o0, 0.01f);
    float o1 = acc1 / den + bb.y;  o1 = LRELU(o1, 0.01f);
    x2p[(size_t)n * 64 + lane] = pack_bf16x2(o0, o1);
}

// ---------------------------------------------------------------------------
// Aggregation layer 2: wave per dst node, TWO edges per iteration (half-wave
// each; lane covers channels {2c,2c+1}); unroll-4 -> 8 edges in flight.
// ---------------------------------------------------------------------------
__global__ __launch_bounds__(256) void aggregate2_kernel(const unsigned* __restrict__ h2p,
                                                         const float* __restrict__ es,
                                                         const float* __restrict__ ed,
                                                         const int* __restrict__ rowstart,
                                                         const int* __restrict__ csr_src,
                                                         const float* __restrict__ b,
                                                         float* __restrict__ out, int N) {
    const int n = (blockIdx.x * 256 + threadIdx.x) >> 6;
    const int lane = threadIdx.x & 63;
    if (n >= N) return;
    const int half = lane >> 5, c = lane & 31;
    const float edv = ed[n];
    const int beg = rowstart[n], end = rowstart[n + 1];

    float acc0 = 0.f, acc1 = 0.f, den = 0.f;
    int j = beg + half;
    for (; j + 6 < end; j += 8) {
        const int s0 = csr_src[j],     s1 = csr_src[j + 2];
        const int s2 = csr_src[j + 4], s3 = csr_src[j + 6];
        const unsigned u0 = h2p[(size_t)s0 * 32 + c];
        const unsigned u1 = h2p[(size_t)s1 * 32 + c];
        const unsigned u2 = h2p[(size_t)s2 * 32 + c];
        const unsigned u3 = h2p[(size_t)s3 * 32 + c];
        const float p0 = __expf(LRELU(es[s0] + edv, 0.2f));
        const float p1 = __expf(LRELU(es[s1] + edv, 0.2f));
        const float p2 = __expf(LRELU(es[s2] + edv, 0.2f));
        const float p3 = __expf(LRELU(es[s3] + edv, 0.2f));
        den += (p0 + p1) + (p2 + p3);
        acc0 = fmaf(p0, bf_lo(u0), fmaf(p1, bf_lo(u1), fmaf(p2, bf_lo(u2), fmaf(p3, bf_lo(u3), acc0))));
        acc1 = fmaf(p0, bf_hi(u0), fmaf(p1, bf_hi(u1), fmaf(p2, bf_hi(u2), fmaf(p3, bf_hi(u3), acc1))));
    }
    for (; j < end; j += 2) {
        const int s = csr_src[j];
        const unsigned u = h2p[(size_t)s * 32 + c];
        const float p = __expf(LRELU(es[s] + edv, 0.2f));
        den += p;
        acc0 = fmaf(p, bf_lo(u), acc0);
        acc1 = fmaf(p, bf_hi(u), acc1);
    }
    den  += __shfl_xor(den, 32);
    acc0 += __shfl_xor(acc0, 32);
    acc1 += __shfl_xor(acc1, 32);
    if (lane < 32) {
        const float2 bb = *(const float2*)&b[c * 2];
        *(float2*)&out[(size_t)n * 64 + c * 2] =
            make_float2(acc0 / den + bb.x, acc1 / den + bb.y);
    }
}

// ---------------------------------------------------------------------------
extern "C" void kernel_launch(void* const* d_in, const int* in_sizes, int n_in,
                              void* d_out, int out_size, void* d_ws, size_t ws_size,
                              hipStream_t stream) {
    const float* x     = (const float*)d_in[0];
    const int*   ei    = (const int*)d_in[1];
    const float* W1    = (const float*)d_in[2];
    const float* asrc1 = (const float*)d_in[3];
    const float* adst1 = (const float*)d_in[4];
    const float* b1    = (const float*)d_in[5];
    const float* W2    = (const float*)d_in[6];
    const float* asrc2 = (const float*)d_in[7];
    const float* adst2 = (const float*)d_in[8];
    const float* b2    = (const float*)d_in[9];
    float* out = (float*)d_out;

    const int N = in_sizes[0] / 128;
    const int E = in_sizes[1] / 2;
    const int Etot = E + N;

    // workspace layout (~83 MB)
    char* p = (char*)d_ws;
    auto alloc = [&](size_t bytes) {
        char* q = p;
        p += (bytes + 255) & ~size_t(255);
        return q;
    };
    unsigned short* h1 = (unsigned short*)alloc((size_t)N * 128 * 2);  // bf16 h1
    unsigned* x2p      = (unsigned*)alloc((size_t)N * 64 * 4);         // bf16x2 x2
    unsigned short* h2 = (unsigned short*)alloc((size_t)N * 64 * 2);   // bf16 h2
    float* es1      = (float*)alloc((size_t)N * 4 * 4);
    float* ed1      = (float*)alloc((size_t)N * 4 * 4);
    float* es2      = (float*)alloc((size_t)N * 4);
    float* ed2      = (float*)alloc((size_t)N * 4);
    int*   deg      = (int*)alloc((size_t)N * 4);
    int*   excl     = (int*)alloc((size_t)N * 4);
    int*   bsum     = (int*)alloc(1024);
    int*   rowstart = (int*)alloc((size_t)(N + 1) * 4);
    int*   rank     = (int*)alloc((size_t)E * 4);
    int*   csr_src  = (int*)alloc((size_t)Etot * 4);
    unsigned* Wb1   = (unsigned*)alloc(2048 * 16);  // 2048 frags x 16B
    unsigned* Wb2   = (unsigned*)alloc(1024 * 16);

    const int nblk16 = (N + 63) / 64;       // MFMA gemms: 4 waves x 16 rows
    const int nwb = (N + 3) / 4;            // wave-per-node kernels
    const int nchunks = (N + 2047) / 2048;  // <= 64 required (N <= 131072)

    // weight prep + degree init
    prep_kernel<<<12, 256, 0, stream>>>(W1, W2, Wb1, Wb2);
    hipMemsetAsync(deg, 0, (size_t)N * 4, stream);

    // layer 1 projection (MFMA) + scores
    gemm1_kernel<<<nblk16, 256, 0, stream>>>(x, Wb1, h1, N);
    escore1_kernel<<<nwb, 256, 0, stream>>>((const unsigned*)h1, asrc1, adst1, es1, ed1, N);

    // CSR by destination (shared by both layers)
    rank_count_kernel<<<512, 256, 0, stream>>>(ei, E, deg, rank);
    scan_p1_kernel<<<nchunks, 256, 0, stream>>>(deg, excl, bsum, N);
    scan_p2_kernel<<<1, 64, 0, stream>>>(bsum, nchunks);
    scan_p3_kernel<<<(N + 255) / 256, 256, 0, stream>>>(excl, bsum, rowstart, N, Etot);
    csr_fill_kernel<<<(Etot + 255) / 256, 256, 0, stream>>>(ei, E, N, rowstart, rank, csr_src);

    // layer 1 aggregation (writes bf16x2 leaky_relu(out1+b1) = layer-2 input)
    aggregate1_kernel<<<nwb, 256, 0, stream>>>((const unsigned*)h1, es1, ed1, rowstart, csr_src, b1, x2p, N);

    // layer 2
    gemm2_kernel<<<nblk16, 256, 0, stream>>>(x2p, Wb2, h2, N);
    escore2_kernel<<<(N / 2 + 3) / 4 + 1, 256, 0, stream>>>((const unsigned*)h2, asrc2, adst2, es2, ed2, N);
    aggregate2_kernel<<<nwb, 256, 0, stream>>>((const unsigned*)h2, es2, ed2, rowstart, csr_src, b2, out, N);
}